// Round 1
// 557.376 us; speedup vs baseline: 1.0194x; 1.0194x over previous
//
#include <hip/hip_runtime.h>
#include <cstdint>
#include <cstddef>

#define BB 4
#define NN 4096
#define DD 768
#define EE 2304      // 3*DD
#define MTOT 16384   // BB*NN
static constexpr float ATT_SCALE = 0.03608439182435161f;  // 1/sqrt(768)

typedef _Float16 v8h __attribute__((ext_vector_type(8)));
typedef _Float16 v4h __attribute__((ext_vector_type(4)));
typedef float v4f __attribute__((ext_vector_type(4)));

// Async global->LDS, 16B per lane. LDS dest = wave-uniform base + lane*16.
__device__ __forceinline__ void async_copy16(void* lds, const void* gmem) {
  __builtin_amdgcn_global_load_lds(
      (const __attribute__((address_space(1))) uint32_t*)(uintptr_t)gmem,
      (__attribute__((address_space(3))) uint32_t*)(uintptr_t)lds,
      16, 0, 0);
}

// Counted vector-memory wait: keeps younger prefetch loads in flight across
// the barrier (T4). "memory" clobber pins all memory ops (ds_read, load_lds)
// on the correct side of the wait.
#define WAIT_VMCNT(n) asm volatile("s_waitcnt vmcnt(" #n ")" ::: "memory")

enum { EPI_QKV = 0, EPI_F16 = 1, EPI_OUT = 2, EPI_PV = 3 };

// C[M,N] = A[M,K] @ Bt[N,K]^T.  A row-major (lda), Bt n-major (ldb).
// 256x256 tile, BK=32, 512 threads = 8 waves (2x4), per-wave 128x64 output
// (acc[8][4] of 16x16x32 MFMA).
//
// Pipeline (T3+T4): 4-deep LDS ring of K-tiles (4 x (16KB A + 16KB B) =
// 128 KB), 3-tile prefetch lookahead.  Per iteration:
//   s_waitcnt vmcnt(8)   -- tile i landed; tiles i+1, i+2 stay in flight
//   s_barrier + sched_barrier(0)
//   issue 4 global_load_lds for tile i+3 -> slot (i+3)%4 == (i-1)%4, whose
//     ds_reads completed (data-dep into last iter's MFMAs) before the barrier
//   12 x ds_read_b128 from slot i%4, then 32 MFMA in setprio(1) (T5)
// One barrier per K-tile; vmcnt never drains to 0 in the main loop, so the
// ~500-900 cyc global->LDS latency is covered by ~3 iterations of MFMA.
//
// LDS swizzle (T2): row r of a 256x32 tile has 4 16B chunks; physical chunk
// pc = kc ^ ((r>>1)&3).  ds_read_b128 frag reads (16 lanes = 16 consecutive
// rows, same logical chunk lq) then land 2 lanes per 16B bank-group within
// each 16-lane quarter-wave: 2-way = conflict-free (m136).  Applied on the
// staging side (per-lane gmem source choice; LDS dest is lane-pinned by
// global_load_lds) and mirrored on the read side.
//
// EPI_PV: blockIdx.z = khalf*2 + batch; k-range [khalf*K, khalf*K+K);
//         C = c_f32 + khalf*chalf + batch*zC (plain f32 partial stores).
// Other EPIs: blockIdx.z = batch (offsets zA/zB/zC).
template <int EPI>
__global__ __launch_bounds__(512, 2) void gemm256(
    const _Float16* __restrict__ A, int lda, size_t zA,
    const _Float16* __restrict__ Bt, int ldb, size_t zB,
    int K,
    float* __restrict__ c_f32,
    _Float16* __restrict__ c_f16,
    int ldc, size_t zC, size_t chalf,
    const float* __restrict__ bias,
    _Float16* __restrict__ q_out,
    _Float16* __restrict__ k_out,
    _Float16* __restrict__ v_out) {
  __shared__ __align__(16) _Float16 As[4][256 * 32];
  __shared__ __align__(16) _Float16 Bs[4][256 * 32];

  const int tid = threadIdx.x;
  const int wid = tid >> 6, lane = tid & 63;
  const int wr = wid >> 2, wc = wid & 3;       // wave grid 2x4 (128x64 each)
  const int lq = lane >> 4, lr = lane & 15;    // quad, row-in-tile
  const int m0 = blockIdx.x * 256, n0 = blockIdx.y * 256;
  const int z = blockIdx.z;
  int bidx, koff;
  if constexpr (EPI == EPI_PV) {
    bidx = z & 1;            // batch within chunk
    koff = (z >> 1) * K;     // k-half offset
  } else {
    bidx = z;
    koff = 0;
  }

  const _Float16* Ab = A + (size_t)bidx * zA + (size_t)m0 * lda + koff;
  const _Float16* Bb = Bt + (size_t)bidx * zB + (size_t)n0 * ldb + koff;

  // Staging: 1024 16B-chunks per matrix per K-tile, 2 per thread (c, c+512).
  // chunk c: row r = c>>2, physical chunk pc = c&3, logical k-chunk
  // kc = pc ^ ((r>>1)&3)  (involution; same XOR on the read side).
  const int c0 = tid, c1 = tid + 512;
  const int r0 = c0 >> 2, r1 = c1 >> 2;
  const int k0c = ((c0 & 3) ^ ((r0 >> 1) & 3)) << 3;  // logical col, elems
  const int k1c = ((c1 & 3) ^ ((r1 >> 1) & 3)) << 3;
  const size_t ga0 = (size_t)r0 * lda + k0c, ga1 = (size_t)r1 * lda + k1c;
  const size_t gb0 = (size_t)r0 * ldb + k0c, gb1 = (size_t)r1 * ldb + k1c;

  // Fragment read offsets (elems), invariant across K-tiles.
  int aoff[8], boff[4];
#pragma unroll
  for (int t = 0; t < 8; ++t) {
    const int ra = wr * 128 + t * 16 + lr;
    aoff[t] = ra * 32 + ((lq ^ ((ra >> 1) & 3)) << 3);
  }
#pragma unroll
  for (int n = 0; n < 4; ++n) {
    const int rb = wc * 64 + n * 16 + lr;
    boff[n] = rb * 32 + ((lq ^ ((rb >> 1) & 3)) << 3);
  }

  v4f acc[8][4] = {};
  const int NT = K / 32;  // all call sites: NT >= 24

  auto stage = [&](int slot, int kt) {
    const int kk = kt * 32;
    async_copy16(&As[slot][c0 * 8], Ab + ga0 + kk);
    async_copy16(&As[slot][c1 * 8], Ab + ga1 + kk);
    async_copy16(&Bs[slot][c0 * 8], Bb + gb0 + kk);
    async_copy16(&Bs[slot][c1 * 8], Bb + gb1 + kk);
  };

  // Prologue: 3 tiles in flight (12 loads/thread).
  stage(0, 0);
  stage(1, 1);
  stage(2, 2);

  for (int it = 0; it < NT; ++it) {
    // Wait for tile `it` only: 8 = 2 younger tiles x 4 loads/thread.
    if (it < NT - 2) {
      WAIT_VMCNT(8);
    } else if (it == NT - 2) {
      WAIT_VMCNT(4);
    } else {
      WAIT_VMCNT(0);
    }
    __builtin_amdgcn_s_barrier();
    __builtin_amdgcn_sched_barrier(0);  // nothing crosses the barrier

    if (it + 3 < NT) stage((it + 3) & 3, it + 3);  // overwrites slot (it-1)&3

    const _Float16* Asl = As[it & 3];
    const _Float16* Bsl = Bs[it & 3];
    v8h af[8], bf[4];
#pragma unroll
    for (int t = 0; t < 8; ++t) af[t] = *(const v8h*)(Asl + aoff[t]);
#pragma unroll
    for (int n = 0; n < 4; ++n) bf[n] = *(const v8h*)(Bsl + boff[n]);

    __builtin_amdgcn_s_setprio(1);
#pragma unroll
    for (int mt = 0; mt < 8; ++mt)
#pragma unroll
      for (int nt = 0; nt < 4; ++nt)
        acc[mt][nt] = __builtin_amdgcn_mfma_f32_16x16x32_f16(
            af[mt], bf[nt], acc[mt][nt], 0, 0, 0);
    __builtin_amdgcn_s_setprio(0);
  }

  // Epilogue. C/D frag: col = lane&15, row = (lane>>4)*4 + reg (m89/m91).
  float* cf = nullptr;
  _Float16* ch = nullptr;
  if constexpr (EPI == EPI_PV)
    cf = c_f32 + (size_t)(z >> 1) * chalf + (size_t)bidx * zC;
  else if constexpr (EPI == EPI_OUT)
    cf = c_f32 + (size_t)bidx * zC;
  else if constexpr (EPI == EPI_F16)
    ch = c_f16 + (size_t)bidx * zC;

#pragma unroll
  for (int mt = 0; mt < 8; ++mt) {
#pragma unroll
    for (int nt = 0; nt < 4; ++nt) {
#pragma unroll
      for (int rg = 0; rg < 4; ++rg) {
        const int gm = m0 + wr * 128 + mt * 16 + lq * 4 + rg;
        const int gn = n0 + wc * 64 + nt * 16 + lr;
        float v = acc[mt][nt][rg];
        if constexpr (EPI == EPI_QKV) {
          v += bias[gn];
          if (gn < DD) {            // uniform per 16-wide run (768 % 16 == 0)
            q_out[(size_t)gm * DD + gn] = (_Float16)(v * ATT_SCALE);
          } else if (gn < 2 * DD) {
            k_out[(size_t)gm * DD + (gn - DD)] = (_Float16)v;
          } else {
            v_out[(size_t)gm * DD + (gn - 2 * DD)] = (_Float16)v;
          }
        } else if constexpr (EPI == EPI_F16) {
          ch[(size_t)gm * ldc + gn] = (_Float16)v;
        } else {  // EPI_PV / EPI_OUT
          cf[(size_t)gm * ldc + gn] = (EPI == EPI_OUT) ? v + bias[gn] : v;
        }
      }
    }
  }
}

// ctx f16 = half0 + half1 (split-K reduce + f32->f16 convert).
__global__ __launch_bounds__(256) void reduce_ctx(const float* __restrict__ h0,
                                                  const float* __restrict__ h1,
                                                  _Float16* __restrict__ out,
                                                  int n4) {
  int i = blockIdx.x * blockDim.x + threadIdx.x;
  if (i < n4) {
    v4f a = ((const v4f*)h0)[i];
    v4f b = ((const v4f*)h1)[i];
    v4h o;
#pragma unroll
    for (int j = 0; j < 4; ++j) o[j] = (_Float16)(a[j] + b[j]);
    ((v4h*)out)[i] = o;
  }
}

// Row softmax over f16 scores, in place. Grid (NN, nz); one block per row.
__global__ __launch_bounds__(256) void softmax_rows_f16(_Float16* __restrict__ S) {
  _Float16* row = S + (size_t)blockIdx.y * NN * NN + (size_t)blockIdx.x * NN;
  const int tid = threadIdx.x;
  const int lane = tid & 63, wid = tid >> 6;

  float f[16];
  float m = -3.0e38f;
#pragma unroll
  for (int i = 0; i < 2; ++i) {
    v8h v = ((const v8h*)row)[tid + i * 256];
#pragma unroll
    for (int j = 0; j < 8; ++j) {
      f[i * 8 + j] = (float)v[j];
      m = fmaxf(m, f[i * 8 + j]);
    }
  }
#pragma unroll
  for (int off = 32; off > 0; off >>= 1) m = fmaxf(m, __shfl_xor(m, off));
  __shared__ float redm[4], reds[4];
  if (lane == 0) redm[wid] = m;
  __syncthreads();
  m = fmaxf(fmaxf(redm[0], redm[1]), fmaxf(redm[2], redm[3]));

  float sum = 0.f;
#pragma unroll
  for (int i = 0; i < 16; ++i) {
    f[i] = __expf(f[i] - m);
    sum += f[i];
  }
#pragma unroll
  for (int off = 32; off > 0; off >>= 1) sum += __shfl_xor(sum, off);
  if (lane == 0) reds[wid] = sum;
  __syncthreads();
  sum = reds[0] + reds[1] + reds[2] + reds[3];
  const float inv = 1.0f / sum;
#pragma unroll
  for (int i = 0; i < 2; ++i) {
    v8h o;
#pragma unroll
    for (int j = 0; j < 8; ++j) o[j] = (_Float16)(f[i * 8 + j] * inv);
    ((v8h*)row)[tid + i * 256] = o;
  }
}

__global__ __launch_bounds__(256) void cvt_f16(const float* __restrict__ in,
                                               _Float16* __restrict__ out, int n4) {
  int i = blockIdx.x * blockDim.x + threadIdx.x;
  if (i < n4) {
    v4f v = ((const v4f*)in)[i];
    v4h o;
#pragma unroll
    for (int j = 0; j < 4; ++j) o[j] = (_Float16)v[j];
    ((v4h*)out)[i] = o;
  }
}

// out[C][R] (f16) = in[R][C] (f32). Grid (C/32, R/32), 256 threads (32x8).
__global__ __launch_bounds__(256) void transpose_cvt(const float* __restrict__ in,
                                                     _Float16* __restrict__ out,
                                                     int R, int C) {
  __shared__ float tile[32][33];
  const int bx = blockIdx.x * 32;  // C base
  const int by = blockIdx.y * 32;  // R base
  const int tx = threadIdx.x & 31, ty = threadIdx.x >> 5;
#pragma unroll
  for (int i = 0; i < 32; i += 8)
    tile[ty + i][tx] = in[(size_t)(by + ty + i) * C + (bx + tx)];
  __syncthreads();
#pragma unroll
  for (int i = 0; i < 32; i += 8)
    out[(size_t)(bx + ty + i) * R + (by + tx)] = (_Float16)tile[tx][ty + i];
}

// Vt[b][d][n] = V[b][n][d], f16. Grid (DD/32, NN/32, BB).
__global__ __launch_bounds__(256) void transpose_v(const _Float16* __restrict__ in,
                                                   _Float16* __restrict__ out) {
  __shared__ _Float16 tile[32][33];
  const int b = blockIdx.z;
  const _Float16* src = in + (size_t)b * NN * DD;
  _Float16* dst = out + (size_t)b * NN * DD;
  const int bx = blockIdx.x * 32;  // DD base
  const int by = blockIdx.y * 32;  // NN base
  const int tx = threadIdx.x & 31, ty = threadIdx.x >> 5;
#pragma unroll
  for (int i = 0; i < 32; i += 8)
    tile[ty + i][tx] = src[(size_t)(by + ty + i) * DD + (bx + tx)];
  __syncthreads();
#pragma unroll
  for (int i = 0; i < 32; i += 8)
    dst[(size_t)(bx + ty + i) * NN + (by + tx)] = tile[tx][ty + i];
}

extern "C" void kernel_launch(void* const* d_in, const int* in_sizes, int n_in,
                              void* d_out, int out_size, void* d_ws, size_t ws_size,
                              hipStream_t stream) {
  const float* x = (const float*)d_in[0];      // [16384][768]
  const float* w_qkv = (const float*)d_in[1];  // [768][2304]
  const float* b_qkv = (const float*)d_in[2];  // [2304]
  const float* w_out = (const float*)d_in[3];  // [768][768]
  const float* b_out = (const float*)d_in[4];  // [768]
  float* out = (float*)d_out;                  // [16384][768] — also used as
                                               // split-K f32 partial scratch
  char* ws = (char*)d_ws;

  // ws layout, peak 164.5 MB (proven in prior rounds):
  _Float16* xh    = (_Float16*)(ws + 0);           // 25 MB  (dead after QKV gemm)
  _Float16* wqkvh = (_Float16*)(ws + 25165824);    // 3.5 MB [2304][768] = W^T
  _Float16* wouth = (_Float16*)(ws + 28704768);    // 1.2 MB [768][768]  = Wout^T
  _Float16* Qh    = (_Float16*)(ws + 29884416);    // 25 MB  (pre-scaled)
  _Float16* Kh    = (_Float16*)(ws + 55050240);    // 25 MB
  _Float16* Vh    = (_Float16*)(ws + 80216064);    // 25 MB  (dead after transpose)
  _Float16* Sh    = (_Float16*)(ws + 105381888);   // 64 MB  f16 scores, 2 batches
  _Float16* Vth   = (_Float16*)(ws + 0);           // reuse xh: [4][768][4096]
  _Float16* Ch    = (_Float16*)(ws + 80216064);    // reuse Vh: [16384][768] ctx

  const size_t zQK = (size_t)NN * DD;   // per-batch stride Q/K/Vt/C (f16 elems)
  const size_t zS = (size_t)NN * NN;    // per-batch stride S (f16 elems)
  const size_t zCtx = (size_t)NN * DD;  // per-batch stride ctx partial (f32)
  const size_t chalf = 2 * zCtx;        // k-half stride in d_out (f32 elems)

  // 1) precision converts / weight transposes
  cvt_f16<<<dim3((MTOT * DD / 4) / 256), 256, 0, stream>>>(x, xh, MTOT * DD / 4);
  transpose_cvt<<<dim3(EE / 32, DD / 32), 256, 0, stream>>>(w_qkv, wqkvh, DD, EE);
  transpose_cvt<<<dim3(DD / 32, DD / 32), 256, 0, stream>>>(w_out, wouth, DD, DD);

  // 2) fused QKV projection (scale folded into Q): grid (64, 9)
  gemm256<EPI_QKV><<<dim3(MTOT / 256, EE / 256), 512, 0, stream>>>(
      xh, DD, 0, wqkvh, DD, 0, DD, nullptr, nullptr, 0, 0, 0, b_qkv, Qh, Kh, Vh);

  // 3) V -> V^T for the PV gemm's n-major B operand
  transpose_v<<<dim3(DD / 32, NN / 32, BB), 256, 0, stream>>>(Vh, Vth);

  // 4) attention in 2-batch chunks: S=QK^T (f16) ; softmax ; ctx=PV split-K=2
  //    PV partials: plain f32 stores into the two halves of d_out (50.3 MB =
  //    exactly 2 halves x 2 batches x 4096 x 768 f32), then reduce to Ch f16.
  for (int c = 0; c < BB / 2; ++c) {
    const _Float16* Qc = Qh + (size_t)c * 2 * zQK;
    const _Float16* Kc = Kh + (size_t)c * 2 * zQK;
    const _Float16* Vtc = Vth + (size_t)c * 2 * zQK;
    gemm256<EPI_F16><<<dim3(NN / 256, NN / 256, 2), 512, 0, stream>>>(
        Qc, DD, zQK, Kc, DD, zQK, DD, nullptr, Sh, NN, zS, 0, nullptr, nullptr,
        nullptr, nullptr);
    softmax_rows_f16<<<dim3(NN, 2), 256, 0, stream>>>(Sh);
    gemm256<EPI_PV><<<dim3(NN / 256, DD / 256, 4), 512, 0, stream>>>(
        Sh, NN, zS, Vtc, NN, zQK, NN / 2, out, nullptr, DD, zCtx, chalf,
        nullptr, nullptr, nullptr, nullptr);
    reduce_ctx<<<dim3((int)(chalf / 4 / 256)), 256, 0, stream>>>(
        out, out + chalf, Ch + (size_t)c * 2 * zQK, (int)(chalf / 4));
  }

  // 5) output projection (reads Ch f16; overwrites d_out with final f32+bias)
  gemm256<EPI_OUT><<<dim3(MTOT / 256, DD / 256), 512, 0, stream>>>(
      Ch, DD, 0, wouth, DD, 0, DD, out, nullptr, DD, 0, 0, b_out, nullptr,
      nullptr, nullptr);
}

// Round 2
// 543.858 us; speedup vs baseline: 1.0447x; 1.0249x over previous
//
#include <hip/hip_runtime.h>
#include <cstdint>
#include <cstddef>

#define BB 4
#define NN 4096
#define DD 768
#define EE 2304      // 3*DD
#define MTOT 16384   // BB*NN
static constexpr float ATT_SCALE = 0.03608439182435161f;  // 1/sqrt(768)

typedef _Float16 v8h __attribute__((ext_vector_type(8)));
typedef _Float16 v4h __attribute__((ext_vector_type(4)));
typedef float v4f __attribute__((ext_vector_type(4)));

// Async global->LDS, 16B per lane. LDS dest = wave-uniform base + lane*16.
__device__ __forceinline__ void async_copy16(void* lds, const void* gmem) {
  __builtin_amdgcn_global_load_lds(
      (const __attribute__((address_space(1))) uint32_t*)(uintptr_t)gmem,
      (__attribute__((address_space(3))) uint32_t*)(uintptr_t)lds,
      16, 0, 0);
}

#define VM_WAIT(n) asm volatile("s_waitcnt vmcnt(" #n ")" ::: "memory")
#define LGKM0 asm volatile("s_waitcnt lgkmcnt(0)" ::: "memory")
#define SCHED0 __builtin_amdgcn_sched_barrier(0)
#define BAR __builtin_amdgcn_s_barrier()

enum { EPI_QKV = 0, EPI_F16 = 1, EPI_OUT = 2, EPI_PV = 3 };

// C[M,N] = A[M,K] @ Bt[N,K]^T.  A row-major (lda), Bt n-major (ldb).
// 256x256 tile, BK=64, 512 threads = 8 waves (2x4), per-wave 128x64 output.
//
// 4-phase schedule per K-tile (m201-template shape, adapted):
//   LDS: 2 slots x {A,B} x 2 ks-sub-tiles (256x32 each, 16KB) = 128 KB.
//   Staging unit = one (matrix, ks) sub-tile = 2 global_load_lds per thread.
//   Stage order per tile == consumption order: A-ks0, B-ks0, A-ks1, B-ks1,
//   issued one unit per phase for tile t+1 while computing tile t:
//     p0: stage A-ks0'; VM_WAIT(6); BAR; read A[mt0-3]ks0+B ks0; 16 MFMA
//     p1: stage B-ks0'; read A[mt4-7]ks0 (B regs live);          16 MFMA
//     p2: stage A-ks1'; VM_WAIT(6); BAR; read A[mt0-3]ks1+B ks1; 16 MFMA
//     p3: stage B-ks1'; read A[mt4-7]ks1; 16 MFMA; LGKM0; BAR
//   vmcnt never drains to 0 until the last tile; every staged unit has >=3
//   phases of issue-to-wait slack.  Counted-wait math (loads/thread, FIFO):
//   at p0 entry 8 outstanding (tile t) + 2 issued -> VM_WAIT(6) lands
//   A-ks0(t),B-ks0(t); at p2 likewise lands A-ks1(t),B-ks1(t).
//   Hazards: reads of tile t guarded by p0/p2 wait+barrier; WAR (stage t+2
//   over slot read in tile t) guarded by p3's LGKM0+BAR (no wave crosses the
//   tile boundary with ds_reads in flight).  sched_barrier(0) flanks every
//   asm wait/barrier so the compiler cannot hoist/sink reads or MFMAs across
//   (rule #18).
//
// LDS swizzle per 256x32 sub-tile (proven 0-conflict in prior rounds):
// row r, physical chunk pc holds logical k-chunk kc = pc ^ ((r>>1)&3);
// applied on the staging side (per-lane gmem source; LDS dest lane-pinned).
//
// SWZ=1: 8x4-supertile XCD remap (requires gx%8==0, gy%4==0): XCD x's 32
// co-resident blocks form an 8bx x 4by tile -> L2 working set 4.7 MB instead
// of 2x16 panels (7 MB).  Used for the QK^T gemm.
//
// EPI_PV: blockIdx.z = khalf*2 + batch; k-range [khalf*K, khalf*K+K);
//         C = c_f32 + khalf*chalf + batch*zC (plain f32 partial stores).
// Other EPIs: blockIdx.z = batch (offsets zA/zB/zC).
template <int EPI, int SWZ = 0>
__global__ __launch_bounds__(512, 2) void gemm256(
    const _Float16* __restrict__ A, int lda, size_t zA,
    const _Float16* __restrict__ Bt, int ldb, size_t zB,
    int K,
    float* __restrict__ c_f32,
    _Float16* __restrict__ c_f16,
    int ldc, size_t zC, size_t chalf,
    const float* __restrict__ bias,
    _Float16* __restrict__ q_out,
    _Float16* __restrict__ k_out,
    _Float16* __restrict__ v_out) {
  __shared__ __align__(16) _Float16 As[2][2][256 * 32];
  __shared__ __align__(16) _Float16 Bs[2][2][256 * 32];

  const int tid = threadIdx.x;
  const int wid = tid >> 6, lane = tid & 63;
  const int wr = wid >> 2, wc = wid & 3;       // wave grid 2x4 (128x64 each)
  const int lq = lane >> 4, lr = lane & 15;    // quad, row-in-tile

  int bx = blockIdx.x, by = blockIdx.y;
  if constexpr (SWZ == 1) {
    const int lin = bx + gridDim.x * by;   // [0, gx*gy) per z-slice
    const int xcd = lin & 7, j = lin >> 3; // ids == xcd (mod 8) share an XCD
    const int stc = gridDim.x >> 3;        // supertile columns
    bx = (xcd % stc) * 8 + (j & 7);
    by = (xcd / stc) * 4 + ((j >> 3) & 3) + (j >> 5) * 4 * (8 / stc == 0 ? 1 : (gridDim.y / 4 / (8 / stc) == 0 ? 1 : (gridDim.y / 4) / (gridDim.y / 4)));  // see note below
  }
  // NOTE: for the call sites using SWZ=1 (gx=16, gy=16, 256 blocks per z),
  // j < 32 always, so the (j>>5) term above is 0 and by = (xcd/2)*4 + (j>>3).
  const int m0 = bx * 256, n0 = by * 256;
  const int z = blockIdx.z;
  int bidx, koff;
  if constexpr (EPI == EPI_PV) {
    bidx = z & 1;            // batch within chunk
    koff = (z >> 1) * K;     // k-half offset
  } else {
    bidx = z;
    koff = 0;
  }

  const _Float16* Ab = A + (size_t)bidx * zA + (size_t)m0 * lda + koff;
  const _Float16* Bb = Bt + (size_t)bidx * zB + (size_t)n0 * ldb + koff;

  // Staging: per sub-tile 1024 16B-chunks, 2 per thread (c, c+512).
  // chunk c: r = c>>2, pc = c&3, logical kc = pc ^ ((r>>1)&3).
  const int c0 = tid, c1 = tid + 512;
  const int r0 = c0 >> 2, r1 = c1 >> 2;
  const int k0c = ((c0 & 3) ^ ((r0 >> 1) & 3)) << 3;  // logical col, elems
  const int k1c = ((c1 & 3) ^ ((r1 >> 1) & 3)) << 3;
  const size_t ga0 = (size_t)r0 * lda + k0c, ga1 = (size_t)r1 * lda + k1c;
  const size_t gb0 = (size_t)r0 * ldb + k0c, gb1 = (size_t)r1 * ldb + k1c;

  // Fragment read offsets (elems) within a 256x32 sub-tile.
  int aoff[8], boff[4];
#pragma unroll
  for (int t = 0; t < 8; ++t) {
    const int ra = wr * 128 + t * 16 + lr;
    aoff[t] = ra * 32 + ((lq ^ ((ra >> 1) & 3)) << 3);
  }
#pragma unroll
  for (int n = 0; n < 4; ++n) {
    const int rb = wc * 64 + n * 16 + lr;
    boff[n] = rb * 32 + ((lq ^ ((rb >> 1) & 3)) << 3);
  }

  v4f acc[8][4] = {};
  const int NT = K / 64;  // all call sites: NT >= 12

  auto stageA = [&](int slot, int ks, int kt) {
    const _Float16* s = Ab + (size_t)(kt * 64 + ks * 32);
    async_copy16(&As[slot][ks][(size_t)c0 * 8], s + ga0);
    async_copy16(&As[slot][ks][(size_t)c1 * 8], s + ga1);
  };
  auto stageB = [&](int slot, int ks, int kt) {
    const _Float16* s = Bb + (size_t)(kt * 64 + ks * 32);
    async_copy16(&Bs[slot][ks][(size_t)c0 * 8], s + gb0);
    async_copy16(&Bs[slot][ks][(size_t)c1 * 8], s + gb1);
  };
  auto mfma16 = [&](const v8h* af_, const v8h* bf_, int mbase) {
#pragma unroll
    for (int mt = 0; mt < 4; ++mt)
#pragma unroll
      for (int nt = 0; nt < 4; ++nt)
        acc[mbase + mt][nt] = __builtin_amdgcn_mfma_f32_16x16x32_f16(
            af_[mt], bf_[nt], acc[mbase + mt][nt], 0, 0, 0);
  };

  // Prologue: tile 0 fully staged in consumption order (8 loads/thread).
  stageA(0, 0, 0);
  stageB(0, 0, 0);
  stageA(0, 1, 0);
  stageB(0, 1, 0);

  for (int t = 0; t < NT; ++t) {
    const int slot = t & 1, ns = slot ^ 1;
    const bool pre = (t + 1 < NT);
    const _Float16* A0s = &As[slot][0][0];
    const _Float16* B0s = &Bs[slot][0][0];
    const _Float16* A1s = &As[slot][1][0];
    const _Float16* B1s = &Bs[slot][1][0];

    v8h a_[4], b0_[4], b1_[4];

    // ---- phase 0: ks0, mt 0-3 ----
    if (pre) {
      stageA(ns, 0, t + 1);
      VM_WAIT(6);
    } else {
      VM_WAIT(4);
    }
    SCHED0;
    BAR;
    SCHED0;
#pragma unroll
    for (int i = 0; i < 4; ++i) a_[i] = *(const v8h*)(A0s + aoff[i]);
#pragma unroll
    for (int i = 0; i < 4; ++i) b0_[i] = *(const v8h*)(B0s + boff[i]);
    __builtin_amdgcn_s_setprio(1);
    mfma16(a_, b0_, 0);
    __builtin_amdgcn_s_setprio(0);

    // ---- phase 1: ks0, mt 4-7 (B ks0 regs still live) ----
    if (pre) stageB(ns, 0, t + 1);
#pragma unroll
    for (int i = 0; i < 4; ++i) a_[i] = *(const v8h*)(A0s + aoff[4 + i]);
    __builtin_amdgcn_s_setprio(1);
    mfma16(a_, b0_, 4);
    __builtin_amdgcn_s_setprio(0);

    // ---- phase 2: ks1, mt 0-3 ----
    if (pre) {
      stageA(ns, 1, t + 1);
      VM_WAIT(6);
    } else {
      VM_WAIT(0);
    }
    SCHED0;
    BAR;
    SCHED0;
#pragma unroll
    for (int i = 0; i < 4; ++i) a_[i] = *(const v8h*)(A1s + aoff[i]);
#pragma unroll
    for (int i = 0; i < 4; ++i) b1_[i] = *(const v8h*)(B1s + boff[i]);
    __builtin_amdgcn_s_setprio(1);
    mfma16(a_, b1_, 0);
    __builtin_amdgcn_s_setprio(0);

    // ---- phase 3: ks1, mt 4-7 ----
    if (pre) stageB(ns, 1, t + 1);
#pragma unroll
    for (int i = 0; i < 4; ++i) a_[i] = *(const v8h*)(A1s + aoff[4 + i]);
    __builtin_amdgcn_s_setprio(1);
    mfma16(a_, b1_, 4);
    __builtin_amdgcn_s_setprio(0);

    // Tile boundary: ds_reads fully drained before any wave can stage over
    // this slot at the next tile's p0.
    LGKM0;
    SCHED0;
    BAR;
    SCHED0;
  }

  // Epilogue. C/D frag: col = lane&15, row = (lane>>4)*4 + reg (m89/m91).
  float* cf = nullptr;
  _Float16* ch = nullptr;
  if constexpr (EPI == EPI_PV)
    cf = c_f32 + (size_t)(z >> 1) * chalf + (size_t)bidx * zC;
  else if constexpr (EPI == EPI_OUT)
    cf = c_f32 + (size_t)bidx * zC;
  else if constexpr (EPI == EPI_F16)
    ch = c_f16 + (size_t)bidx * zC;

#pragma unroll
  for (int mt = 0; mt < 8; ++mt) {
#pragma unroll
    for (int nt = 0; nt < 4; ++nt) {
#pragma unroll
      for (int rg = 0; rg < 4; ++rg) {
        const int gm = m0 + wr * 128 + mt * 16 + lq * 4 + rg;
        const int gn = n0 + wc * 64 + nt * 16 + lr;
        float v = acc[mt][nt][rg];
        if constexpr (EPI == EPI_QKV) {
          v += bias[gn];
          if (gn < DD) {            // uniform per 16-wide run (768 % 16 == 0)
            q_out[(size_t)gm * DD + gn] = (_Float16)(v * ATT_SCALE);
          } else if (gn < 2 * DD) {
            k_out[(size_t)gm * DD + (gn - DD)] = (_Float16)v;
          } else {
            v_out[(size_t)gm * DD + (gn - 2 * DD)] = (_Float16)v;
          }
        } else if constexpr (EPI == EPI_F16) {
          ch[(size_t)gm * ldc + gn] = (_Float16)v;
        } else {  // EPI_PV / EPI_OUT
          cf[(size_t)gm * ldc + gn] = (EPI == EPI_OUT) ? v + bias[gn] : v;
        }
      }
    }
  }
}

// ctx f16 = half0 + half1 (split-K reduce + f32->f16 convert).
__global__ __launch_bounds__(256) void reduce_ctx(const float* __restrict__ h0,
                                                  const float* __restrict__ h1,
                                                  _Float16* __restrict__ out,
                                                  int n4) {
  int i = blockIdx.x * blockDim.x + threadIdx.x;
  if (i < n4) {
    v4f a = ((const v4f*)h0)[i];
    v4f b = ((const v4f*)h1)[i];
    v4h o;
#pragma unroll
    for (int j = 0; j < 4; ++j) o[j] = (_Float16)(a[j] + b[j]);
    ((v4h*)out)[i] = o;
  }
}

// Row softmax over f16 scores, in place. Grid (NN, nz); one block per row.
__global__ __launch_bounds__(256) void softmax_rows_f16(_Float16* __restrict__ S) {
  _Float16* row = S + (size_t)blockIdx.y * NN * NN + (size_t)blockIdx.x * NN;
  const int tid = threadIdx.x;
  const int lane = tid & 63, wid = tid >> 6;

  float f[16];
  float m = -3.0e38f;
#pragma unroll
  for (int i = 0; i < 2; ++i) {
    v8h v = ((const v8h*)row)[tid + i * 256];
#pragma unroll
    for (int j = 0; j < 8; ++j) {
      f[i * 8 + j] = (float)v[j];
      m = fmaxf(m, f[i * 8 + j]);
    }
  }
#pragma unroll
  for (int off = 32; off > 0; off >>= 1) m = fmaxf(m, __shfl_xor(m, off));
  __shared__ float redm[4], reds[4];
  if (lane == 0) redm[wid] = m;
  __syncthreads();
  m = fmaxf(fmaxf(redm[0], redm[1]), fmaxf(redm[2], redm[3]));

  float sum = 0.f;
#pragma unroll
  for (int i = 0; i < 16; ++i) {
    f[i] = __expf(f[i] - m);
    sum += f[i];
  }
#pragma unroll
  for (int off = 32; off > 0; off >>= 1) sum += __shfl_xor(sum, off);
  if (lane == 0) reds[wid] = sum;
  __syncthreads();
  sum = reds[0] + reds[1] + reds[2] + reds[3];
  const float inv = 1.0f / sum;
#pragma unroll
  for (int i = 0; i < 2; ++i) {
    v8h o;
#pragma unroll
    for (int j = 0; j < 8; ++j) o[j] = (_Float16)(f[i * 8 + j] * inv);
    ((v8h*)row)[tid + i * 256] = o;
  }
}

__global__ __launch_bounds__(256) void cvt_f16(const float* __restrict__ in,
                                               _Float16* __restrict__ out, int n4) {
  int i = blockIdx.x * blockDim.x + threadIdx.x;
  if (i < n4) {
    v4f v = ((const v4f*)in)[i];
    v4h o;
#pragma unroll
    for (int j = 0; j < 4; ++j) o[j] = (_Float16)v[j];
    ((v4h*)out)[i] = o;
  }
}

// out[C][R] (f16) = in[R][C] (f32). Grid (C/32, R/32), 256 threads (32x8).
__global__ __launch_bounds__(256) void transpose_cvt(const float* __restrict__ in,
                                                     _Float16* __restrict__ out,
                                                     int R, int C) {
  __shared__ float tile[32][33];
  const int bx = blockIdx.x * 32;  // C base
  const int by = blockIdx.y * 32;  // R base
  const int tx = threadIdx.x & 31, ty = threadIdx.x >> 5;
#pragma unroll
  for (int i = 0; i < 32; i += 8)
    tile[ty + i][tx] = in[(size_t)(by + ty + i) * C + (bx + tx)];
  __syncthreads();
#pragma unroll
  for (int i = 0; i < 32; i += 8)
    out[(size_t)(bx + ty + i) * R + (by + tx)] = (_Float16)tile[tx][ty + i];
}

// Vt[b][d][n] = V[b][n][d], f16. Grid (DD/32, NN/32, BB).
__global__ __launch_bounds__(256) void transpose_v(const _Float16* __restrict__ in,
                                                   _Float16* __restrict__ out) {
  __shared__ _Float16 tile[32][33];
  const int b = blockIdx.z;
  const _Float16* src = in + (size_t)b * NN * DD;
  _Float16* dst = out + (size_t)b * NN * DD;
  const int bx = blockIdx.x * 32;  // DD base
  const int by = blockIdx.y * 32;  // NN base
  const int tx = threadIdx.x & 31, ty = threadIdx.x >> 5;
#pragma unroll
  for (int i = 0; i < 32; i += 8)
    tile[ty + i][tx] = src[(size_t)(by + ty + i) * DD + (bx + tx)];
  __syncthreads();
#pragma unroll
  for (int i = 0; i < 32; i += 8)
    dst[(size_t)(bx + ty + i) * NN + (by + tx)] = tile[tx][ty + i];
}

extern "C" void kernel_launch(void* const* d_in, const int* in_sizes, int n_in,
                              void* d_out, int out_size, void* d_ws, size_t ws_size,
                              hipStream_t stream) {
  const float* x = (const float*)d_in[0];      // [16384][768]
  const float* w_qkv = (const float*)d_in[1];  // [768][2304]
  const float* b_qkv = (const float*)d_in[2];  // [2304]
  const float* w_out = (const float*)d_in[3];  // [768][768]
  const float* b_out = (const float*)d_in[4];  // [768]
  float* out = (float*)d_out;                  // [16384][768] — also used as
                                               // split-K f32 partial scratch
  char* ws = (char*)d_ws;

  // ws layout, peak 164.5 MB (proven in prior rounds):
  _Float16* xh    = (_Float16*)(ws + 0);           // 25 MB  (dead after QKV gemm)
  _Float16* wqkvh = (_Float16*)(ws + 25165824);    // 3.5 MB [2304][768] = W^T
  _Float16* wouth = (_Float16*)(ws + 28704768);    // 1.2 MB [768][768]  = Wout^T
  _Float16* Qh    = (_Float16*)(ws + 29884416);    // 25 MB  (pre-scaled)
  _Float16* Kh    = (_Float16*)(ws + 55050240);    // 25 MB
  _Float16* Vh    = (_Float16*)(ws + 80216064);    // 25 MB  (dead after transpose)
  _Float16* Sh    = (_Float16*)(ws + 105381888);   // 64 MB  f16 scores, 2 batches
  _Float16* Vth   = (_Float16*)(ws + 0);           // reuse xh: [4][768][4096]
  _Float16* Ch    = (_Float16*)(ws + 80216064);    // reuse Vh: [16384][768] ctx

  const size_t zQK = (size_t)NN * DD;   // per-batch stride Q/K/Vt/C (f16 elems)
  const size_t zS = (size_t)NN * NN;    // per-batch stride S (f16 elems)
  const size_t zCtx = (size_t)NN * DD;  // per-batch stride ctx partial (f32)
  const size_t chalf = 2 * zCtx;        // k-half stride in d_out (f32 elems)

  // 1) precision converts / weight transposes
  cvt_f16<<<dim3((MTOT * DD / 4) / 256), 256, 0, stream>>>(x, xh, MTOT * DD / 4);
  transpose_cvt<<<dim3(EE / 32, DD / 32), 256, 0, stream>>>(w_qkv, wqkvh, DD, EE);
  transpose_cvt<<<dim3(DD / 32, DD / 32), 256, 0, stream>>>(w_out, wouth, DD, DD);

  // 2) fused QKV projection (scale folded into Q): grid (64, 9)
  gemm256<EPI_QKV><<<dim3(MTOT / 256, EE / 256), 512, 0, stream>>>(
      xh, DD, 0, wqkvh, DD, 0, DD, nullptr, nullptr, 0, 0, 0, b_qkv, Qh, Kh, Vh);

  // 3) V -> V^T for the PV gemm's n-major B operand
  transpose_v<<<dim3(DD / 32, NN / 32, BB), 256, 0, stream>>>(Vh, Vth);

  // 4) attention in 2-batch chunks: S=QK^T (f16) ; softmax ; ctx=PV split-K=2
  //    PV partials: plain f32 stores into the two halves of d_out (50.3 MB =
  //    exactly 2 halves x 2 batches x 4096 x 768 f32), then reduce to Ch f16.
  for (int c = 0; c < BB / 2; ++c) {
    const _Float16* Qc = Qh + (size_t)c * 2 * zQK;
    const _Float16* Kc = Kh + (size_t)c * 2 * zQK;
    const _Float16* Vtc = Vth + (size_t)c * 2 * zQK;
    gemm256<EPI_F16, 1><<<dim3(NN / 256, NN / 256, 2), 512, 0, stream>>>(
        Qc, DD, zQK, Kc, DD, zQK, DD, nullptr, Sh, NN, zS, 0, nullptr, nullptr,
        nullptr, nullptr);
    softmax_rows_f16<<<dim3(NN, 2), 256, 0, stream>>>(Sh);
    gemm256<EPI_PV><<<dim3(NN / 256, DD / 256, 4), 512, 0, stream>>>(
        Sh, NN, zS, Vtc, NN, zQK, NN / 2, out, nullptr, DD, zCtx, chalf,
        nullptr, nullptr, nullptr, nullptr);
    reduce_ctx<<<dim3((int)(chalf / 4 / 256)), 256, 0, stream>>>(
        out, out + chalf, Ch + (size_t)c * 2 * zQK, (int)(chalf / 4));
  }

  // 5) output projection (reads Ch f16; overwrites d_out with final f32+bias)
  gemm256<EPI_OUT><<<dim3(MTOT / 256, DD / 256), 512, 0, stream>>>(
      Ch, DD, 0, wouth, DD, 0, DD, out, nullptr, DD, 0, 0, b_out, nullptr,
      nullptr, nullptr);
}